// Round 9
// baseline (260.866 us; speedup 1.0000x reference)
//
#include <hip/hip_runtime.h>
#include <hip/hip_bf16.h>

#define NROWS   131072
#define DDIM    64
#define KCODES  512

// MFMA-path geometry
#define RPB     64                 // rows per block
#define NBLK    (NROWS / RPB)      // 2048 blocks
#define CAP     8
#define THRESH  0.04f

// ws float offsets (parts first so the fallback fits small ws)
#define WS_PART 0                  // 2048 floats
#define WS_WT   2048               // 32768 floats: wT[k][d]
#define WS_WSQ  34816              // 512 floats
#define WS_WTH  35328              // 16384 float-slots = 32768 ushort (bf16-hi)
#define WS_WTL  51712              // 16384 float-slots (bf16-lo)
#define WS_END  68096
#define WS_NEED_MFMA ((size_t)WS_END * sizeof(float))   // 272384 B
#define WS_NEED_FALL ((size_t)35328 * sizeof(float))    // 141312 B

#define NBLK_FB 1024               // fallback kernel geometry (r3-verified)

typedef __attribute__((ext_vector_type(8))) short short8;
typedef __attribute__((ext_vector_type(4))) float f32x4;

static __device__ __forceinline__ unsigned short f2bf(float v) {
  union { __hip_bfloat16 b; unsigned short u; } cv;
  cv.b = __float2bfloat16(v);
  return cv.u;
}
static __device__ __forceinline__ float bf2f(unsigned short u) {
  union { float f; unsigned v; } r;
  r.v = ((unsigned)u) << 16;
  return r.f;
}

// bit-exact sequential-d 64-element dot (numpy/BLAS K-order), batched loads.
// r8 BUG WAS HERE: previous version covered only d=0..31. Now all 16 float4s.
static __device__ __forceinline__ float dot64(const float* __restrict__ xr,
                                              const float* __restrict__ wk) {
  const float4* __restrict__ w4 = (const float4*)wk;
  const float4* __restrict__ x4 = (const float4*)xr;
  float d = 0.f;
  // first half: d = 0..31 (8 float4s batched -> one wait group)
  {
    float4 wa0 = w4[0], wa1 = w4[1], wa2 = w4[2], wa3 = w4[3];
    float4 wa4 = w4[4], wa5 = w4[5], wa6 = w4[6], wa7 = w4[7];
    float4 xa0 = x4[0], xa1 = x4[1], xa2 = x4[2], xa3 = x4[3];
    float4 xa4 = x4[4], xa5 = x4[5], xa6 = x4[6], xa7 = x4[7];
    d = __builtin_fmaf(xa0.x, wa0.x, d); d = __builtin_fmaf(xa0.y, wa0.y, d);
    d = __builtin_fmaf(xa0.z, wa0.z, d); d = __builtin_fmaf(xa0.w, wa0.w, d);
    d = __builtin_fmaf(xa1.x, wa1.x, d); d = __builtin_fmaf(xa1.y, wa1.y, d);
    d = __builtin_fmaf(xa1.z, wa1.z, d); d = __builtin_fmaf(xa1.w, wa1.w, d);
    d = __builtin_fmaf(xa2.x, wa2.x, d); d = __builtin_fmaf(xa2.y, wa2.y, d);
    d = __builtin_fmaf(xa2.z, wa2.z, d); d = __builtin_fmaf(xa2.w, wa2.w, d);
    d = __builtin_fmaf(xa3.x, wa3.x, d); d = __builtin_fmaf(xa3.y, wa3.y, d);
    d = __builtin_fmaf(xa3.z, wa3.z, d); d = __builtin_fmaf(xa3.w, wa3.w, d);
    d = __builtin_fmaf(xa4.x, wa4.x, d); d = __builtin_fmaf(xa4.y, wa4.y, d);
    d = __builtin_fmaf(xa4.z, wa4.z, d); d = __builtin_fmaf(xa4.w, wa4.w, d);
    d = __builtin_fmaf(xa5.x, wa5.x, d); d = __builtin_fmaf(xa5.y, wa5.y, d);
    d = __builtin_fmaf(xa5.z, wa5.z, d); d = __builtin_fmaf(xa5.w, wa5.w, d);
    d = __builtin_fmaf(xa6.x, wa6.x, d); d = __builtin_fmaf(xa6.y, wa6.y, d);
    d = __builtin_fmaf(xa6.z, wa6.z, d); d = __builtin_fmaf(xa6.w, wa6.w, d);
    d = __builtin_fmaf(xa7.x, wa7.x, d); d = __builtin_fmaf(xa7.y, wa7.y, d);
    d = __builtin_fmaf(xa7.z, wa7.z, d); d = __builtin_fmaf(xa7.w, wa7.w, d);
  }
  // second half: d = 32..63
  {
    float4 wb0 = w4[8],  wb1 = w4[9],  wb2 = w4[10], wb3 = w4[11];
    float4 wb4 = w4[12], wb5 = w4[13], wb6 = w4[14], wb7 = w4[15];
    float4 xb0 = x4[8],  xb1 = x4[9],  xb2 = x4[10], xb3 = x4[11];
    float4 xb4 = x4[12], xb5 = x4[13], xb6 = x4[14], xb7 = x4[15];
    d = __builtin_fmaf(xb0.x, wb0.x, d); d = __builtin_fmaf(xb0.y, wb0.y, d);
    d = __builtin_fmaf(xb0.z, wb0.z, d); d = __builtin_fmaf(xb0.w, wb0.w, d);
    d = __builtin_fmaf(xb1.x, wb1.x, d); d = __builtin_fmaf(xb1.y, wb1.y, d);
    d = __builtin_fmaf(xb1.z, wb1.z, d); d = __builtin_fmaf(xb1.w, wb1.w, d);
    d = __builtin_fmaf(xb2.x, wb2.x, d); d = __builtin_fmaf(xb2.y, wb2.y, d);
    d = __builtin_fmaf(xb2.z, wb2.z, d); d = __builtin_fmaf(xb2.w, wb2.w, d);
    d = __builtin_fmaf(xb3.x, wb3.x, d); d = __builtin_fmaf(xb3.y, wb3.y, d);
    d = __builtin_fmaf(xb3.z, wb3.z, d); d = __builtin_fmaf(xb3.w, wb3.w, d);
    d = __builtin_fmaf(xb4.x, wb4.x, d); d = __builtin_fmaf(xb4.y, wb4.y, d);
    d = __builtin_fmaf(xb4.z, wb4.z, d); d = __builtin_fmaf(xb4.w, wb4.w, d);
    d = __builtin_fmaf(xb5.x, wb5.x, d); d = __builtin_fmaf(xb5.y, wb5.y, d);
    d = __builtin_fmaf(xb5.z, wb5.z, d); d = __builtin_fmaf(xb5.w, wb5.w, d);
    d = __builtin_fmaf(xb6.x, wb6.x, d); d = __builtin_fmaf(xb6.y, wb6.y, d);
    d = __builtin_fmaf(xb6.z, wb6.z, d); d = __builtin_fmaf(xb6.w, wb6.w, d);
    d = __builtin_fmaf(xb7.x, wb7.x, d); d = __builtin_fmaf(xb7.y, wb7.y, d);
    d = __builtin_fmaf(xb7.z, wb7.z, d); d = __builtin_fmaf(xb7.w, wb7.w, d);
  }
  return d;
}

// wT[k][d] transpose + wsq in numpy axis-0 sequential order (verified r3-r7)
__global__ void vq_prep_base(const float* __restrict__ w, float* __restrict__ wT,
                             float* __restrict__ wsq) {
  int g = blockIdx.x * 256 + threadIdx.x;  // g = k*64 + d
  wT[g] = w[(g & 63) * KCODES + (g >> 6)];
  if (g < KCODES) {
    float s = __fmul_rn(w[g], w[g]);
    for (int dd = 1; dd < DDIM; ++dd) {
      float v = w[dd * KCODES + g];
      s = __fadd_rn(s, __fmul_rn(v, v));
    }
    wsq[g] = s;
  }
}

// bf16 hi/lo split of wT (verified r7)
__global__ void vq_prep_bf16(const float* __restrict__ wT,
                             unsigned short* __restrict__ wTh,
                             unsigned short* __restrict__ wTl) {
  int g = blockIdx.x * 256 + threadIdx.x;
  float v = wT[g];
  unsigned short h = f2bf(v);
  wTh[g] = h;
  wTl[g] = f2bf(v - bf2f(h));
}

// ---------------- MFMA main (r7-verified numerics, r8 schedule, dot64 fixed) ----------------
__global__ __launch_bounds__(256) void vq_mfma(
    const float* __restrict__ x, const float* __restrict__ wT,
    const float* __restrict__ wsq, const unsigned short* __restrict__ wTh,
    const unsigned short* __restrict__ wTl, float* __restrict__ out_idx,
    float* __restrict__ out_zq, float* __restrict__ out_ze,
    float* __restrict__ lossPart) {
  __shared__ float xf[RPB * 68];     // fp32 x tile, stride 68 (16B-aligned)
  __shared__ float sumf_s[RPB];
  __shared__ int   idx_s[RPB];
  __shared__ int   cnt[RPB];
  __shared__ int   cand[RPB][CAP];
  __shared__ float loss_s[4];

  const int tid = threadIdx.x;
  const int wv = tid >> 6;     // wave owns rows [wv*16, wv*16+16)
  const int lane = tid & 63;
  const int lr = lane & 15;    // A-row / B-col within 16x16 tile
  const int kg = lane >> 4;    // k-group 0..3
  const int rowBase = blockIdx.x * RPB;
  const float* xb = x + (size_t)rowBase * DDIM;

  // ---- stage x tile (block-wide; the only cross-wave LDS dependency) ----
#pragma unroll
  for (int j = 0; j < 4; ++j) {
    int off = j * 1024 + tid * 4;
    float4 v = *(const float4*)(xb + off);
    int row = off >> 6, d0 = off & 63;
    *(float4*)&xf[row * 68 + d0] = v;
  }
  if (lane < 16) cnt[wv * 16 + lane] = 0;   // wave-local
  __syncthreads();

  // ---- A fragments (hi/lo bf16), verified layout: row=lr, k=kg*8+j (+32) ----
  short8 ah0, ah1, al0, al1;
  {
    const float* s0 = &xf[(wv * 16 + lr) * 68 + kg * 8];
#pragma unroll
    for (int j = 0; j < 8; ++j) {
      float v = s0[j];
      unsigned short h = f2bf(v);
      ah0[j] = (short)h;
      al0[j] = (short)f2bf(v - bf2f(h));
      float v1 = s0[32 + j];
      unsigned short h1 = f2bf(v1);
      ah1[j] = (short)h1;
      al1[j] = (short)f2bf(v1 - bf2f(h1));
    }
  }

  // ---- sumf per row (wave-local; numpy pairwise-8, verified) ----
  if (lane < 16) {
    const float* xr = &xf[(wv * 16 + lane) * 68];
    float rr[8];
#pragma unroll
    for (int j = 0; j < 8; ++j) rr[j] = __fmul_rn(xr[j], xr[j]);
#pragma unroll
    for (int b = 1; b < 8; ++b)
#pragma unroll
      for (int j = 0; j < 8; ++j)
        rr[j] = __fadd_rn(rr[j], __fmul_rn(xr[b * 8 + j], xr[b * 8 + j]));
    float s01 = __fadd_rn(rr[0], rr[1]), s23 = __fadd_rn(rr[2], rr[3]);
    float s45 = __fadd_rn(rr[4], rr[5]), s67 = __fadd_rn(rr[6], rr[7]);
    sumf_s[wv * 16 + lane] = __fadd_rn(__fadd_rn(s01, s23), __fadd_rn(s45, s67));
  }

#define LDBH(n, half) (*(const short8*)(wTh + (size_t)(n) * 1024 + lr * 64 + (half) * 32 + kg * 8))
#define LDBL(n, half) (*(const short8*)(wTl + (size_t)(n) * 1024 + lr * 64 + (half) * 32 + kg * 8))

  // ---- pass 1: running min of score = wsq - 2*dot_approx (software-prefetched B) ----
  float rmin[4] = {3.4e38f, 3.4e38f, 3.4e38f, 3.4e38f};
  {
    short8 bh0 = LDBH(0, 0), bh1 = LDBH(0, 1), bl0 = LDBL(0, 0), bl1 = LDBL(0, 1);
    float wsqk = wsq[lr];
    for (int n = 0; n < 32; ++n) {
      int np = n < 31 ? n + 1 : 31;
      short8 nh0 = LDBH(np, 0), nh1 = LDBH(np, 1);
      short8 nl0 = LDBL(np, 0), nl1 = LDBL(np, 1);
      float nws = wsq[np * 16 + lr];
      f32x4 acc = {0.f, 0.f, 0.f, 0.f};
      acc = __builtin_amdgcn_mfma_f32_16x16x32_bf16(ah0, bh0, acc, 0, 0, 0);
      acc = __builtin_amdgcn_mfma_f32_16x16x32_bf16(al0, bh0, acc, 0, 0, 0);
      acc = __builtin_amdgcn_mfma_f32_16x16x32_bf16(ah0, bl0, acc, 0, 0, 0);
      acc = __builtin_amdgcn_mfma_f32_16x16x32_bf16(ah1, bh1, acc, 0, 0, 0);
      acc = __builtin_amdgcn_mfma_f32_16x16x32_bf16(al1, bh1, acc, 0, 0, 0);
      acc = __builtin_amdgcn_mfma_f32_16x16x32_bf16(ah1, bl1, acc, 0, 0, 0);
#pragma unroll
      for (int q = 0; q < 4; ++q)
        rmin[q] = fminf(rmin[q], __builtin_fmaf(-2.0f, acc[q], wsqk));
      bh0 = nh0; bh1 = nh1; bl0 = nl0; bl1 = nl1; wsqk = nws;
    }
  }
  // row-min across the 16 cols, then pre-add threshold
#pragma unroll
  for (int q = 0; q < 4; ++q) {
    float v = rmin[q];
#pragma unroll
    for (int s = 1; s < 16; s <<= 1) v = fminf(v, __shfl_xor(v, s));
    rmin[q] = v + THRESH;
  }

  // ---- pass 2: bitwise-identical recompute, collect candidates ----
  {
    short8 bh0 = LDBH(0, 0), bh1 = LDBH(0, 1), bl0 = LDBL(0, 0), bl1 = LDBL(0, 1);
    float wsqk = wsq[lr];
    for (int n = 0; n < 32; ++n) {
      int np = n < 31 ? n + 1 : 31;
      short8 nh0 = LDBH(np, 0), nh1 = LDBH(np, 1);
      short8 nl0 = LDBL(np, 0), nl1 = LDBL(np, 1);
      float nws = wsq[np * 16 + lr];
      f32x4 acc = {0.f, 0.f, 0.f, 0.f};
      acc = __builtin_amdgcn_mfma_f32_16x16x32_bf16(ah0, bh0, acc, 0, 0, 0);
      acc = __builtin_amdgcn_mfma_f32_16x16x32_bf16(al0, bh0, acc, 0, 0, 0);
      acc = __builtin_amdgcn_mfma_f32_16x16x32_bf16(ah0, bl0, acc, 0, 0, 0);
      acc = __builtin_amdgcn_mfma_f32_16x16x32_bf16(ah1, bh1, acc, 0, 0, 0);
      acc = __builtin_amdgcn_mfma_f32_16x16x32_bf16(al1, bh1, acc, 0, 0, 0);
      acc = __builtin_amdgcn_mfma_f32_16x16x32_bf16(ah1, bl1, acc, 0, 0, 0);
      const int kcol = n * 16 + lr;
#pragma unroll
      for (int q = 0; q < 4; ++q) {
        float sc = __builtin_fmaf(-2.0f, acc[q], wsqk);
        if (sc <= rmin[q]) {
          int rl = wv * 16 + kg * 4 + q;   // verified C layout: row = kg*4+q
          int slot = atomicAdd(&cnt[rl], 1);
          if (slot < CAP) cand[rl][slot] = kcol;
        }
      }
      bh0 = nh0; bh1 = nh1; bl0 = nl0; bl1 = nl1; wsqk = nws;
    }
  }

  // ---- exact rescore (wave-local rows; 4 lanes per row; bit-exact numpy tree) ----
  {
    const int myrow = wv * 16 + (lane >> 2);
    const int sub = lane & 3;
    const int cnr = cnt[myrow];
    const float* xr = &xf[myrow * 68];
    const float sf = sumf_s[myrow];
    float bd = 3.4e38f;
    int bk = 0x7fffffff;
    if (cnr <= CAP) {
#pragma unroll 1
      for (int s0 = 0; s0 < CAP; s0 += 4) {
        if (!__any(s0 + sub < cnr)) break;
        if (s0 + sub < cnr) {
          int k = cand[myrow][s0 + sub];
          float dot = dot64(xr, wT + k * DDIM);
          float dist = __fadd_rn(__fsub_rn(sf, __fmul_rn(2.0f, dot)), wsq[k]);
          if (dist < bd || (dist == bd && k < bk)) { bd = dist; bk = k; }
        }
      }
    } else {  // overflow (~never): exact full scan, still bit-exact
      for (int k = sub; k < KCODES; k += 4) {
        float dot = dot64(xr, wT + k * DDIM);
        float dist = __fadd_rn(__fsub_rn(sf, __fmul_rn(2.0f, dot)), wsq[k]);
        if (dist < bd || (dist == bd && k < bk)) { bd = dist; bk = k; }
      }
    }
#pragma unroll
    for (int s = 1; s < 4; s <<= 1) {   // lexicographic (dist, k) min
      float od = __shfl_xor(bd, s);
      int ok = __shfl_xor(bk, s);
      if (od < bd || (od == bd && ok < bk)) { bd = od; bk = ok; }
    }
    if (sub == 0) idx_s[myrow] = bk;
  }

  // ---- epilogue (wave-local): float4 z_q_st / z_e, loss partial, indices ----
  float lsum = 0.f;
#pragma unroll
  for (int t = 0; t < 4; ++t) {
    int row = wv * 16 + t * 4 + (lane >> 4);
    int d0 = (lane & 15) * 4;
    int kf = idx_s[row];
    float4 xv = *(const float4*)&xf[row * 68 + d0];
    float4 wq = *(const float4*)&wT[kf * DDIM + d0];
    float4 zq;
    zq.x = __fadd_rn(xv.x, __fsub_rn(wq.x, xv.x));   // z_e + (z_q - z_e), per-op
    zq.y = __fadd_rn(xv.y, __fsub_rn(wq.y, xv.y));
    zq.z = __fadd_rn(xv.z, __fsub_rn(wq.z, xv.z));
    zq.w = __fadd_rn(xv.w, __fsub_rn(wq.w, xv.w));
    size_t go = (size_t)(rowBase + row) * DDIM + d0;
    *(float4*)(out_zq + go) = zq;
    *(float4*)(out_ze + go) = xv;
    float e0 = __fsub_rn(wq.x, xv.x), e1 = __fsub_rn(wq.y, xv.y);
    float e2 = __fsub_rn(wq.z, xv.z), e3 = __fsub_rn(wq.w, xv.w);
    lsum = __builtin_fmaf(e0, e0, lsum);
    lsum = __builtin_fmaf(e1, e1, lsum);
    lsum = __builtin_fmaf(e2, e2, lsum);
    lsum = __builtin_fmaf(e3, e3, lsum);
  }
#pragma unroll
  for (int s = 1; s < 64; s <<= 1) lsum += __shfl_xor(lsum, s);
  if (lane == 0) loss_s[wv] = lsum;
  if (lane < 16)
    out_idx[rowBase + wv * 16 + lane] = (float)idx_s[wv * 16 + lane];
  __syncthreads();
  if (tid == 0)
    lossPart[blockIdx.x] =
        __fadd_rn(__fadd_rn(__fadd_rn(loss_s[0], loss_s[1]), loss_s[2]), loss_s[3]);
}

// ---------------- fallback: round-3 verified kernel ----------------
template <int USE_WT, int LOSS_ATOMIC>
__global__ __launch_bounds__(256) void vq_fb(
    const float* __restrict__ x, const float* __restrict__ w,
    const float* __restrict__ wT,
    float* __restrict__ out_idx, float* __restrict__ out_zq,
    float* __restrict__ out_ze, float* __restrict__ lossOut) {
  __shared__ float xT[4][32 * 64];
  __shared__ float wtile[64 * 64];
  __shared__ float __attribute__((aligned(16))) sq_s[64];
  __shared__ float sumf_s[4][32];
  __shared__ int   idx_s[4][32];
  __shared__ float lsum_s[4];

  const int tid = threadIdx.x;
  const int wv = tid >> 6;
  const int lane = tid & 63;
  const int r = lane >> 3;
  const int c = lane & 7;
  const int rowBase = (blockIdx.x * 4 + wv) * 32;
  const float* xblk = x + (size_t)rowBase * DDIM;

#pragma unroll
  for (int j = 0; j < 8; ++j) {
    int off = j * 256 + lane * 4;
    float4 v = *(const float4*)(xblk + off);
    int row = off >> 6, d0 = off & 63;
    xT[wv][(d0 + 0) * 32 + row] = v.x;
    xT[wv][(d0 + 1) * 32 + row] = v.y;
    xT[wv][(d0 + 2) * 32 + row] = v.z;
    xT[wv][(d0 + 3) * 32 + row] = v.w;
  }
  __syncthreads();

  if (lane < 32) {
    float rr[8];
#pragma unroll
    for (int j = 0; j < 8; ++j) {
      float v = xT[wv][j * 32 + lane];
      rr[j] = __fmul_rn(v, v);
    }
#pragma unroll
    for (int blk = 1; blk < 8; ++blk)
#pragma unroll
      for (int j = 0; j < 8; ++j) {
        float v = xT[wv][(blk * 8 + j) * 32 + lane];
        rr[j] = __fadd_rn(rr[j], __fmul_rn(v, v));
      }
    float s01 = __fadd_rn(rr[0], rr[1]);
    float s23 = __fadd_rn(rr[2], rr[3]);
    float s45 = __fadd_rn(rr[4], rr[5]);
    float s67 = __fadd_rn(rr[6], rr[7]);
    sumf_s[wv][lane] = __fadd_rn(__fadd_rn(s01, s23), __fadd_rn(s45, s67));
  }

  float minv[4] = {3.4e38f, 3.4e38f, 3.4e38f, 3.4e38f};
  int mink[4] = {0, 0, 0, 0};

  for (int ct = 0; ct < 8; ++ct) {
#pragma unroll
    for (int j = 0; j < 4; ++j) {
      int off = j * 1024 + tid * 4;
      int d0 = off >> 6, kk = off & 63;
      *(float4*)&wtile[off] = *(const float4*)&w[d0 * KCODES + ct * 64 + kk];
    }
    __syncthreads();

    if (tid < 64) {
      float v0 = wtile[tid];
      float s = __fmul_rn(v0, v0);
      for (int d = 1; d < 64; ++d) {
        float v = wtile[d * 64 + tid];
        s = __fadd_rn(s, __fmul_rn(v, v));
      }
      sq_s[tid] = s;
    }

    float acc[4][8];
#pragma unroll
    for (int i = 0; i < 4; ++i)
#pragma unroll
      for (int j = 0; j < 8; ++j) acc[i][j] = 0.f;

#pragma unroll 4
    for (int d = 0; d < DDIM; ++d) {
      float4 a4 = *(const float4*)&xT[wv][d * 32 + r * 4];
      float4 b0 = *(const float4*)&wtile[d * 64 + c * 8];
      float4 b1 = *(const float4*)&wtile[d * 64 + c * 8 + 4];
      float a[4] = {a4.x, a4.y, a4.z, a4.w};
      float b[8] = {b0.x, b0.y, b0.z, b0.w, b1.x, b1.y, b1.z, b1.w};
#pragma unroll
      for (int i = 0; i < 4; ++i)
#pragma unroll
        for (int j = 0; j < 8; ++j)
          acc[i][j] = __builtin_fmaf(a[i], b[j], acc[i][j]);
    }
    __syncthreads();

#pragma unroll
    for (int i = 0; i < 4; ++i) {
      float sf = sumf_s[wv][r * 4 + i];
#pragma unroll
      for (int j = 0; j < 8; ++j) {
        float dist = __fadd_rn(__fsub_rn(sf, __fmul_rn(2.0f, acc[i][j])), sq_s[c * 8 + j]);
        int k = ct * 64 + c * 8 + j;
        if (dist < minv[i]) { minv[i] = dist; mink[i] = k; }
      }
    }
  }

#pragma unroll
  for (int i = 0; i < 4; ++i) {
    float v = minv[i];
    int kk = mink[i];
    for (int s = 1; s < 8; s <<= 1) {
      float ov = __shfl_xor(v, s);
      int ok = __shfl_xor(kk, s);
      if (ov < v || (ov == v && ok < kk)) { v = ov; kk = ok; }
    }
    if (c == 0) idx_s[wv][r * 4 + i] = kk;
  }

  float lsum = 0.f;
  for (int rowi = 0; rowi < 32; ++rowi) {
    int k = idx_s[wv][rowi];
    size_t go = (size_t)(rowBase + rowi) * DDIM + lane;
    float xv = xblk[rowi * DDIM + lane];
    float wvv = USE_WT ? wT[k * DDIM + lane] : w[lane * KCODES + k];
    out_zq[go] = __fadd_rn(xv, __fsub_rn(wvv, xv));
    out_ze[go] = xv;
    float dd = __fsub_rn(wvv, xv);
    lsum = __builtin_fmaf(dd, dd, lsum);
  }
#pragma unroll
  for (int s = 1; s < 64; s <<= 1) lsum += __shfl_xor(lsum, s);
  if (lane == 0) lsum_s[wv] = lsum;
  __syncthreads();
  if (tid == 0) {
    float part = __fadd_rn(__fadd_rn(__fadd_rn(lsum_s[0], lsum_s[1]), lsum_s[2]), lsum_s[3]);
    if (LOSS_ATOMIC) atomicAdd(lossOut, part);
    else lossOut[blockIdx.x] = part;
  }
  if (lane < 32)
    out_idx[rowBase + lane] = (float)idx_s[wv][lane];
}

// loss = 2 * sum / (N*D) = sum * 2^-22
__global__ void vq_loss(const float* __restrict__ part, int npart,
                        float* __restrict__ out_loss) {
  float s = 0.f;
  for (int i = threadIdx.x; i < npart; i += 64) s += part[i];
#pragma unroll
  for (int t = 1; t < 64; t <<= 1) s += __shfl_xor(s, t);
  if (threadIdx.x == 0) out_loss[0] = s * (1.0f / 4194304.0f);
}

extern "C" void kernel_launch(void* const* d_in, const int* in_sizes, int n_in,
                              void* d_out, int out_size, void* d_ws, size_t ws_size,
                              hipStream_t stream) {
  const float* x = (const float*)d_in[0];
  const float* w = (const float*)d_in[1];
  float* ob = (float*)d_out;
  float* out_idx = ob;
  float* out_zq = ob + NROWS;
  float* out_ze = out_zq + (size_t)NROWS * DDIM;
  float* out_loss = out_ze + (size_t)NROWS * DDIM;
  float* wsf = (float*)d_ws;

  if (ws_size >= WS_NEED_MFMA) {
    vq_prep_base<<<128, 256, 0, stream>>>(w, wsf + WS_WT, wsf + WS_WSQ);
    vq_prep_bf16<<<128, 256, 0, stream>>>(wsf + WS_WT,
                                          (unsigned short*)(wsf + WS_WTH),
                                          (unsigned short*)(wsf + WS_WTL));
    vq_mfma<<<NBLK, 256, 0, stream>>>(x, wsf + WS_WT, wsf + WS_WSQ,
                                      (const unsigned short*)(wsf + WS_WTH),
                                      (const unsigned short*)(wsf + WS_WTL),
                                      out_idx, out_zq, out_ze, wsf + WS_PART);
    vq_loss<<<1, 64, 0, stream>>>(wsf + WS_PART, NBLK, out_loss);
  } else if (ws_size >= WS_NEED_FALL) {
    vq_prep_base<<<128, 256, 0, stream>>>(w, wsf + WS_WT, wsf + WS_WSQ);
    vq_fb<1, 0><<<NBLK_FB, 256, 0, stream>>>(x, w, wsf + WS_WT, out_idx,
                                             out_zq, out_ze, wsf + WS_PART);
    vq_loss<<<1, 64, 0, stream>>>(wsf + WS_PART, NBLK_FB, out_loss);
  } else {
    hipMemsetAsync(out_loss, 0, sizeof(float), stream);
    vq_fb<0, 1><<<NBLK_FB, 256, 0, stream>>>(x, w, nullptr, out_idx,
                                             out_zq, out_ze, out_loss);
    vq_loss<<<1, 64, 0, stream>>>(out_loss, 1, out_loss);
  }
}

// Round 10
// 96.999 us; speedup vs baseline: 2.6894x; 2.6894x over previous
//
#include <hip/hip_runtime.h>
#include <hip/hip_bf16.h>

#define NROWS   131072
#define DDIM    64
#define KCODES  512

// MFMA-path geometry
#define RPB     128                // rows per block
#define NBLK    (NROWS / RPB)      // 1024 blocks
#define CAP     16
#define THRESH  0.04f

// ws float offsets (unchanged from r9)
#define WS_PART 0                  // 2048 floats
#define WS_WT   2048               // 32768 floats: wT[k][d]
#define WS_WSQ  34816              // 512 floats
#define WS_WTH  35328              // 16384 float-slots = 32768 ushort (bf16-hi)
#define WS_WTL  51712              // 16384 float-slots (bf16-lo)
#define WS_END  68096
#define WS_NEED_MFMA ((size_t)WS_END * sizeof(float))   // 272384 B
#define WS_NEED_FALL ((size_t)35328 * sizeof(float))    // 141312 B

#define NBLK_FB 1024               // fallback kernel geometry (r3-verified)

typedef __attribute__((ext_vector_type(8))) short short8;
typedef __attribute__((ext_vector_type(4))) float f32x4;

static __device__ __forceinline__ unsigned short f2bf(float v) {
  union { __hip_bfloat16 b; unsigned short u; } cv;
  cv.b = __float2bfloat16(v);
  return cv.u;
}
static __device__ __forceinline__ float bf2f(unsigned short u) {
  union { float f; unsigned v; } r;
  r.v = ((unsigned)u) << 16;
  return r.f;
}

// bit-exact sequential-d 64-element dot (numpy/BLAS K-order), batched loads (r9-fixed)
static __device__ __forceinline__ float dot64(const float* __restrict__ xr,
                                              const float* __restrict__ wk) {
  const float4* __restrict__ w4 = (const float4*)wk;
  const float4* __restrict__ x4 = (const float4*)xr;
  float d = 0.f;
  {
    float4 wa0 = w4[0], wa1 = w4[1], wa2 = w4[2], wa3 = w4[3];
    float4 wa4 = w4[4], wa5 = w4[5], wa6 = w4[6], wa7 = w4[7];
    float4 xa0 = x4[0], xa1 = x4[1], xa2 = x4[2], xa3 = x4[3];
    float4 xa4 = x4[4], xa5 = x4[5], xa6 = x4[6], xa7 = x4[7];
    d = __builtin_fmaf(xa0.x, wa0.x, d); d = __builtin_fmaf(xa0.y, wa0.y, d);
    d = __builtin_fmaf(xa0.z, wa0.z, d); d = __builtin_fmaf(xa0.w, wa0.w, d);
    d = __builtin_fmaf(xa1.x, wa1.x, d); d = __builtin_fmaf(xa1.y, wa1.y, d);
    d = __builtin_fmaf(xa1.z, wa1.z, d); d = __builtin_fmaf(xa1.w, wa1.w, d);
    d = __builtin_fmaf(xa2.x, wa2.x, d); d = __builtin_fmaf(xa2.y, wa2.y, d);
    d = __builtin_fmaf(xa2.z, wa2.z, d); d = __builtin_fmaf(xa2.w, wa2.w, d);
    d = __builtin_fmaf(xa3.x, wa3.x, d); d = __builtin_fmaf(xa3.y, wa3.y, d);
    d = __builtin_fmaf(xa3.z, wa3.z, d); d = __builtin_fmaf(xa3.w, wa3.w, d);
    d = __builtin_fmaf(xa4.x, wa4.x, d); d = __builtin_fmaf(xa4.y, wa4.y, d);
    d = __builtin_fmaf(xa4.z, wa4.z, d); d = __builtin_fmaf(xa4.w, wa4.w, d);
    d = __builtin_fmaf(xa5.x, wa5.x, d); d = __builtin_fmaf(xa5.y, wa5.y, d);
    d = __builtin_fmaf(xa5.z, wa5.z, d); d = __builtin_fmaf(xa5.w, wa5.w, d);
    d = __builtin_fmaf(xa6.x, wa6.x, d); d = __builtin_fmaf(xa6.y, wa6.y, d);
    d = __builtin_fmaf(xa6.z, wa6.z, d); d = __builtin_fmaf(xa6.w, wa6.w, d);
    d = __builtin_fmaf(xa7.x, wa7.x, d); d = __builtin_fmaf(xa7.y, wa7.y, d);
    d = __builtin_fmaf(xa7.z, wa7.z, d); d = __builtin_fmaf(xa7.w, wa7.w, d);
  }
  {
    float4 wb0 = w4[8],  wb1 = w4[9],  wb2 = w4[10], wb3 = w4[11];
    float4 wb4 = w4[12], wb5 = w4[13], wb6 = w4[14], wb7 = w4[15];
    float4 xb0 = x4[8],  xb1 = x4[9],  xb2 = x4[10], xb3 = x4[11];
    float4 xb4 = x4[12], xb5 = x4[13], xb6 = x4[14], xb7 = x4[15];
    d = __builtin_fmaf(xb0.x, wb0.x, d); d = __builtin_fmaf(xb0.y, wb0.y, d);
    d = __builtin_fmaf(xb0.z, wb0.z, d); d = __builtin_fmaf(xb0.w, wb0.w, d);
    d = __builtin_fmaf(xb1.x, wb1.x, d); d = __builtin_fmaf(xb1.y, wb1.y, d);
    d = __builtin_fmaf(xb1.z, wb1.z, d); d = __builtin_fmaf(xb1.w, wb1.w, d);
    d = __builtin_fmaf(xb2.x, wb2.x, d); d = __builtin_fmaf(xb2.y, wb2.y, d);
    d = __builtin_fmaf(xb2.z, wb2.z, d); d = __builtin_fmaf(xb2.w, wb2.w, d);
    d = __builtin_fmaf(xb3.x, wb3.x, d); d = __builtin_fmaf(xb3.y, wb3.y, d);
    d = __builtin_fmaf(xb3.z, wb3.z, d); d = __builtin_fmaf(xb3.w, wb3.w, d);
    d = __builtin_fmaf(xb4.x, wb4.x, d); d = __builtin_fmaf(xb4.y, wb4.y, d);
    d = __builtin_fmaf(xb4.z, wb4.z, d); d = __builtin_fmaf(xb4.w, wb4.w, d);
    d = __builtin_fmaf(xb5.x, wb5.x, d); d = __builtin_fmaf(xb5.y, wb5.y, d);
    d = __builtin_fmaf(xb5.z, wb5.z, d); d = __builtin_fmaf(xb5.w, wb5.w, d);
    d = __builtin_fmaf(xb6.x, wb6.x, d); d = __builtin_fmaf(xb6.y, wb6.y, d);
    d = __builtin_fmaf(xb6.z, wb6.z, d); d = __builtin_fmaf(xb6.w, wb6.w, d);
    d = __builtin_fmaf(xb7.x, wb7.x, d); d = __builtin_fmaf(xb7.y, wb7.y, d);
    d = __builtin_fmaf(xb7.z, wb7.z, d); d = __builtin_fmaf(xb7.w, wb7.w, d);
  }
  return d;
}

// wT[k][d] transpose + wsq in numpy axis-0 sequential order (verified r3-r9)
__global__ void vq_prep_base(const float* __restrict__ w, float* __restrict__ wT,
                             float* __restrict__ wsq) {
  int g = blockIdx.x * 256 + threadIdx.x;  // g = k*64 + d
  wT[g] = w[(g & 63) * KCODES + (g >> 6)];
  if (g < KCODES) {
    float s = __fmul_rn(w[g], w[g]);
    for (int dd = 1; dd < DDIM; ++dd) {
      float v = w[dd * KCODES + g];
      s = __fadd_rn(s, __fmul_rn(v, v));
    }
    wsq[g] = s;
  }
}

// bf16 hi/lo split of wT (verified r7-r9)
__global__ void vq_prep_bf16(const float* __restrict__ wT,
                             unsigned short* __restrict__ wTh,
                             unsigned short* __restrict__ wTl) {
  int g = blockIdx.x * 256 + threadIdx.x;
  float v = wT[g];
  unsigned short h = f2bf(v);
  wTh[g] = h;
  wTl[g] = f2bf(v - bf2f(h));
}

// ---------- MFMA main: LDS-staged B (dbuf + XOR swizzle), single pass ----------
__global__ __launch_bounds__(256) void vq_mfma(
    const float* __restrict__ x, const float* __restrict__ wT,
    const float* __restrict__ wsq, const unsigned short* __restrict__ wTh,
    const unsigned short* __restrict__ wTl, float* __restrict__ out_idx,
    float* __restrict__ out_zq, float* __restrict__ out_ze,
    float* __restrict__ lossPart) {
  __shared__ float xf[RPB * 68];                              // 34816 B
  __shared__ __attribute__((aligned(16))) char Bb[2][16384];  // [buf][hi 8K | lo 8K]
  __shared__ float wsq_s[KCODES];                             // 2048 B
  __shared__ float sumf_s[RPB];
  __shared__ int   idx_s[RPB];
  __shared__ int   cnt[RPB];
  __shared__ int   cand[RPB][CAP];                            // 8192 B
  __shared__ float loss_s[4];

  const int tid = threadIdx.x;
  const int wv = tid >> 6;     // wave owns rows [wv*32, wv*32+32)
  const int lane = tid & 63;
  const int lr = lane & 15;    // A-row / B-col within 16x16 tile
  const int kg = lane >> 4;    // k-group 0..3
  const int rowBase = blockIdx.x * RPB;
  const float* xb = x + (size_t)rowBase * DDIM;

  // ---- stage x tile + wsq + zero cnt ----
#pragma unroll
  for (int j = 0; j < 8; ++j) {
    int off = j * 1024 + tid * 4;
    float4 v = *(const float4*)(xb + off);
    int row = off >> 6, d0 = off & 63;
    *(float4*)&xf[row * 68 + d0] = v;
  }
  if (tid < 128) {
    cnt[tid] = 0;
    *(float4*)&wsq_s[tid * 4] = *(const float4*)&wsq[tid * 4];
  }

  // ---- B staging: regs <- global (tile t), then swizzled ds_write ----
  const char* gH = (const char*)wTh;
  const char* gL = (const char*)wTl;
  float4 rH0, rH1, rL0, rL1;
#define LOADT(t)                                                   \
  {                                                                \
    const char* bh = gH + (size_t)(t) * 8192;                      \
    const char* bl = gL + (size_t)(t) * 8192;                      \
    rH0 = *(const float4*)(bh + tid * 16);                         \
    rH1 = *(const float4*)(bh + 4096 + tid * 16);                  \
    rL0 = *(const float4*)(bl + tid * 16);                         \
    rL1 = *(const float4*)(bl + 4096 + tid * 16);                  \
  }
  // swizzle: byte-in-row ^= (cc&7)<<4  (both write & read sides)
  const int p0 = tid * 16, p1 = 4096 + tid * 16;
  const int cc0 = p0 >> 7, cc1 = p1 >> 7;
  const int w0 = cc0 * 128 + ((p0 & 127) ^ ((cc0 & 7) << 4));
  const int w1 = cc1 * 128 + ((p1 & 127) ^ ((cc1 & 7) << 4));
#define WRITET(buf)                                                \
  {                                                                \
    *(float4*)(Bb[buf] + w0) = rH0;                                \
    *(float4*)(Bb[buf] + w1) = rH1;                                \
    *(float4*)(Bb[buf] + 8192 + w0) = rL0;                         \
    *(float4*)(Bb[buf] + 8192 + w1) = rL1;                         \
  }

  LOADT(0);
  __syncthreads();   // xf, wsq_s, cnt visible

  // ---- A fragments (r7-verified layout & build) ----
  short8 ah[2][2], al[2][2];
#pragma unroll
  for (int m = 0; m < 2; ++m)
#pragma unroll
    for (int kb = 0; kb < 2; ++kb) {
      const float* src = &xf[(wv * 32 + m * 16 + lr) * 68 + kb * 32 + kg * 8];
      short8 h, l;
#pragma unroll
      for (int j = 0; j < 8; ++j) {
        float v = src[j];
        unsigned short hu = f2bf(v);
        h[j] = (short)hu;
        l[j] = (short)f2bf(v - bf2f(hu));
      }
      ah[m][kb] = h;
      al[m][kb] = l;
    }

  // ---- sumf per row (r7-verified numpy pairwise-8) ----
  if (lane < 32) {
    const float* xr = &xf[(wv * 32 + lane) * 68];
    float rr[8];
#pragma unroll
    for (int j = 0; j < 8; ++j) rr[j] = __fmul_rn(xr[j], xr[j]);
#pragma unroll
    for (int b = 1; b < 8; ++b)
#pragma unroll
      for (int j = 0; j < 8; ++j)
        rr[j] = __fadd_rn(rr[j], __fmul_rn(xr[b * 8 + j], xr[b * 8 + j]));
    float s01 = __fadd_rn(rr[0], rr[1]), s23 = __fadd_rn(rr[2], rr[3]);
    float s45 = __fadd_rn(rr[4], rr[5]), s67 = __fadd_rn(rr[6], rr[7]);
    sumf_s[wv * 32 + lane] = __fadd_rn(__fadd_rn(s01, s23), __fadd_rn(s45, s67));
  }

  WRITET(0);
  LOADT(1);
  __syncthreads();   // buf0 ready

  // ---- single-pass K loop: 8 tiles x 64 codes ----
  float rmin[2][4];
#pragma unroll
  for (int m = 0; m < 2; ++m)
#pragma unroll
    for (int q = 0; q < 4; ++q) rmin[m][q] = 3.4e38f;

  for (int t = 0; t < 8; ++t) {
    const char* bufc = Bb[t & 1];
    float sc[2][4][4];
#pragma unroll
    for (int n = 0; n < 4; ++n) {
      const int cc = n * 16 + lr;
      const int rowb = cc * 128;
      const int srow = (cc & 7) << 4;
      short8 bh0 = *(const short8*)(bufc + rowb + ((kg * 16) ^ srow));
      short8 bh1 = *(const short8*)(bufc + rowb + ((64 + kg * 16) ^ srow));
      short8 bl0 = *(const short8*)(bufc + 8192 + rowb + ((kg * 16) ^ srow));
      short8 bl1 = *(const short8*)(bufc + 8192 + rowb + ((64 + kg * 16) ^ srow));
      float wsqk = wsq_s[t * 64 + cc];
#pragma unroll
      for (int m = 0; m < 2; ++m) {
        f32x4 acc = {0.f, 0.f, 0.f, 0.f};
        acc = __builtin_amdgcn_mfma_f32_16x16x32_bf16(ah[m][0], bh0, acc, 0, 0, 0);
        acc = __builtin_amdgcn_mfma_f32_16x16x32_bf16(al[m][0], bh0, acc, 0, 0, 0);
        acc = __builtin_amdgcn_mfma_f32_16x16x32_bf16(ah[m][0], bl0, acc, 0, 0, 0);
        acc = __builtin_amdgcn_mfma_f32_16x16x32_bf16(ah[m][1], bh1, acc, 0, 0, 0);
        acc = __builtin_amdgcn_mfma_f32_16x16x32_bf16(al[m][1], bh1, acc, 0, 0, 0);
        acc = __builtin_amdgcn_mfma_f32_16x16x32_bf16(ah[m][1], bl1, acc, 0, 0, 0);
#pragma unroll
        for (int q = 0; q < 4; ++q)
          sc[m][n][q] = __builtin_fmaf(-2.0f, acc[q], wsqk);
      }
    }
    // per-tile row-min update + candidate collection (superset of 2-pass set)
#pragma unroll
    for (int m = 0; m < 2; ++m)
#pragma unroll
      for (int q = 0; q < 4; ++q) {
        float tm = fminf(fminf(sc[m][0][q], sc[m][1][q]),
                         fminf(sc[m][2][q], sc[m][3][q]));
#pragma unroll
        for (int s = 1; s < 16; s <<= 1) tm = fminf(tm, __shfl_xor(tm, s));
        float rm = fminf(rmin[m][q], tm);
        rmin[m][q] = rm;
        float thr = rm + THRESH;
        int rl = wv * 32 + m * 16 + kg * 4 + q;   // verified C layout
#pragma unroll
        for (int n = 0; n < 4; ++n) {
          if (sc[m][n][q] <= thr) {
            int slot = atomicAdd(&cnt[rl], 1);
            if (slot < CAP) cand[rl][slot] = t * 64 + n * 16 + lr;
          }
        }
      }
    __syncthreads();             // all waves done reading buf[t&1]
    if (t < 7) {
      WRITET((t + 1) & 1);       // vmcnt wait on LOADT(t+1) regs handled by compiler
      if (t < 6) LOADT(t + 2);   // 2-tile-deep prefetch
      __syncthreads();           // writes visible before next tile's reads
    }
  }

  // ---- exact rescore (r9-verified logic; 2 halves of the wave's 32 rows) ----
#pragma unroll 1
  for (int half = 0; half < 2; ++half) {
    const int myrow = wv * 32 + half * 16 + (lane >> 2);
    const int sub = lane & 3;
    const int cnr = cnt[myrow];
    const float* xr = &xf[myrow * 68];
    const float sf = sumf_s[myrow];
    float bd = 3.4e38f;
    int bk = 0x7fffffff;
    if (cnr <= CAP) {
#pragma unroll 1
      for (int s0 = 0; s0 < CAP; s0 += 4) {
        if (!__any(s0 + sub < cnr)) break;
        if (s0 + sub < cnr) {
          int k = cand[myrow][s0 + sub];
          float dot = dot64(xr, wT + k * DDIM);
          float dist = __fadd_rn(__fsub_rn(sf, __fmul_rn(2.0f, dot)), wsq[k]);
          if (dist < bd || (dist == bd && k < bk)) { bd = dist; bk = k; }
        }
      }
    } else {  // overflow (~never): exact full scan, still bit-exact
      for (int k = sub; k < KCODES; k += 4) {
        float dot = dot64(xr, wT + k * DDIM);
        float dist = __fadd_rn(__fsub_rn(sf, __fmul_rn(2.0f, dot)), wsq[k]);
        if (dist < bd || (dist == bd && k < bk)) { bd = dist; bk = k; }
      }
    }
#pragma unroll
    for (int s = 1; s < 4; s <<= 1) {   // lexicographic (dist, k) min
      float od = __shfl_xor(bd, s);
      int ok = __shfl_xor(bk, s);
      if (od < bd || (od == bd && ok < bk)) { bd = od; bk = ok; }
    }
    if (sub == 0) idx_s[myrow] = bk;
  }

  // ---- epilogue (r9-verified pattern, 32 rows/wave) ----
  float lsum = 0.f;
#pragma unroll
  for (int tt = 0; tt < 8; ++tt) {
    int row = wv * 32 + tt * 4 + (lane >> 4);
    int d0 = (lane & 15) * 4;
    int kf = idx_s[row];
    float4 xv = *(const float4*)&xf[row * 68 + d0];
    float4 wq = *(const float4*)&wT[kf * DDIM + d0];
    float4 zq;
    zq.x = __fadd_rn(xv.x, __fsub_rn(wq.x, xv.x));   // z_e + (z_q - z_e), per-op
    zq.y = __fadd_rn(xv.y, __fsub_rn(wq.y, xv.y));
    zq.z = __fadd_rn(xv.z, __fsub_rn(wq.z, xv.z));
    zq.w = __fadd_rn(xv.w, __fsub_rn(wq.w, xv.w));
    size_t go = (size_t)(rowBase + row) * DDIM + d0;
    *(float4*)(out_zq + go) = zq;
    *(float4*)(out_ze + go) = xv;
    float e0 = __fsub_rn(wq.x, xv.x), e1 = __fsub_rn(wq.y, xv.y);
    float e2 = __fsub_rn(wq.z, xv.z), e3 = __fsub_rn(wq.w, xv.w);
    lsum = __builtin_fmaf(e0, e0, lsum);
    lsum = __builtin_fmaf(e1, e1, lsum);
    lsum = __builtin_fmaf(e2, e2, lsum);
    lsum = __builtin_fmaf(e3, e3, lsum);
  }
#pragma unroll
  for (int s = 1; s < 64; s <<= 1) lsum += __shfl_xor(lsum, s);
  if (lane == 0) loss_s[wv] = lsum;
  if (lane < 32)
    out_idx[rowBase + wv * 32 + lane] = (float)idx_s[wv * 32 + lane];
  __syncthreads();
  if (tid == 0)
    lossPart[blockIdx.x] =
        __fadd_rn(__fadd_rn(__fadd_rn(loss_s[0], loss_s[1]), loss_s[2]), loss_s[3]);
}

// ---------------- fallback: round-3 verified kernel ----------------
template <int USE_WT, int LOSS_ATOMIC>
__global__ __launch_bounds__(256) void vq_fb(
    const float* __restrict__ x, const float* __restrict__ w,
    const float* __restrict__ wT,
    float* __restrict__ out_idx, float* __restrict__ out_zq,
    float* __restrict__ out_ze, float* __restrict__ lossOut) {
  __shared__ float xT[4][32 * 64];
  __shared__ float wtile[64 * 64];
  __shared__ float __attribute__((aligned(16))) sq_s[64];
  __shared__ float sumf_s[4][32];
  __shared__ int   idx_s[4][32];
  __shared__ float lsum_s[4];

  const int tid = threadIdx.x;
  const int wv = tid >> 6;
  const int lane = tid & 63;
  const int r = lane >> 3;
  const int c = lane & 7;
  const int rowBase = (blockIdx.x * 4 + wv) * 32;
  const float* xblk = x + (size_t)rowBase * DDIM;

#pragma unroll
  for (int j = 0; j < 8; ++j) {
    int off = j * 256 + lane * 4;
    float4 v = *(const float4*)(xblk + off);
    int row = off >> 6, d0 = off & 63;
    xT[wv][(d0 + 0) * 32 + row] = v.x;
    xT[wv][(d0 + 1) * 32 + row] = v.y;
    xT[wv][(d0 + 2) * 32 + row] = v.z;
    xT[wv][(d0 + 3) * 32 + row] = v.w;
  }
  __syncthreads();

  if (lane < 32) {
    float rr[8];
#pragma unroll
    for (int j = 0; j < 8; ++j) {
      float v = xT[wv][j * 32 + lane];
      rr[j] = __fmul_rn(v, v);
    }
#pragma unroll
    for (int blk = 1; blk < 8; ++blk)
#pragma unroll
      for (int j = 0; j < 8; ++j) {
        float v = xT[wv][(blk * 8 + j) * 32 + lane];
        rr[j] = __fadd_rn(rr[j], __fmul_rn(v, v));
      }
    float s01 = __fadd_rn(rr[0], rr[1]);
    float s23 = __fadd_rn(rr[2], rr[3]);
    float s45 = __fadd_rn(rr[4], rr[5]);
    float s67 = __fadd_rn(rr[6], rr[7]);
    sumf_s[wv][lane] = __fadd_rn(__fadd_rn(s01, s23), __fadd_rn(s45, s67));
  }

  float minv[4] = {3.4e38f, 3.4e38f, 3.4e38f, 3.4e38f};
  int mink[4] = {0, 0, 0, 0};

  for (int ct = 0; ct < 8; ++ct) {
#pragma unroll
    for (int j = 0; j < 4; ++j) {
      int off = j * 1024 + tid * 4;
      int d0 = off >> 6, kk = off & 63;
      *(float4*)&wtile[off] = *(const float4*)&w[d0 * KCODES + ct * 64 + kk];
    }
    __syncthreads();

    if (tid < 64) {
      float v0 = wtile[tid];
      float s = __fmul_rn(v0, v0);
      for (int d = 1; d < 64; ++d) {
        float v = wtile[d * 64 + tid];
        s = __fadd_rn(s, __fmul_rn(v, v));
      }
      sq_s[tid] = s;
    }

    float acc[4][8];
#pragma unroll
    for (int i = 0; i < 4; ++i)
#pragma unroll
      for (int j = 0; j < 8; ++j) acc[i][j] = 0.f;

#pragma unroll 4
    for (int d = 0; d < DDIM; ++d) {
      float4 a4 = *(const float4*)&xT[wv][d * 32 + r * 4];
      float4 b0 = *(const float4*)&wtile[d * 64 + c * 8];
      float4 b1 = *(const float4*)&wtile[d * 64 + c * 8 + 4];
      float a[4] = {a4.x, a4.y, a4.z, a4.w};
      float b[8] = {b0.x, b0.y, b0.z, b0.w, b1.x, b1.y, b1.z, b1.w};
#pragma unroll
      for (int i = 0; i < 4; ++i)
#pragma unroll
        for (int j = 0; j < 8; ++j)
          acc[i][j] = __builtin_fmaf(a[i], b[j], acc[i][j]);
    }
    __syncthreads();

#pragma unroll
    for (int i = 0; i < 4; ++i) {
      float sf = sumf_s[wv][r * 4 + i];
#pragma unroll
      for (int j = 0; j < 8; ++j) {
        float dist = __fadd_rn(__fsub_rn(sf, __fmul_rn(2.0f, acc[i][j])), sq_s[c * 8 + j]);
        int k = ct * 64 + c * 8 + j;
        if (dist < minv[i]) { minv[i] = dist; mink[i] = k; }
      }
    }
  }

#pragma unroll
  for (int i = 0; i < 4; ++i) {
    float v = minv[i];
    int kk = mink[i];
    for (int s = 1; s < 8; s <<= 1) {
      float ov = __shfl_xor(v, s);
      int ok = __shfl_xor(kk, s);
      if (ov < v || (ov == v && ok < kk)) { v = ov; kk = ok; }
    }
    if (c == 0) idx_s[wv][r * 4 + i] = kk;
  }

  float lsum = 0.f;
  for (int rowi = 0; rowi < 32; ++rowi) {
    int k = idx_s[wv][rowi];
    size_t go = (size_t)(rowBase + rowi) * DDIM + lane;
    float xv = xblk[rowi * DDIM + lane];
    float wvv = USE_WT ? wT[k * DDIM + lane] : w[lane * KCODES + k];
    out_zq[go] = __fadd_rn(xv, __fsub_rn(wvv, xv));
    out_ze[go] = xv;
    float dd = __fsub_rn(wvv, xv);
    lsum = __builtin_fmaf(dd, dd, lsum);
  }
#pragma unroll
  for (int s = 1; s < 64; s <<= 1) lsum += __shfl_xor(lsum, s);
  if (lane == 0) lsum_s[wv] = lsum;
  __syncthreads();
  if (tid == 0) {
    float part = __fadd_rn(__fadd_rn(__fadd_rn(lsum_s[0], lsum_s[1]), lsum_s[2]), lsum_s[3]);
    if (LOSS_ATOMIC) atomicAdd(lossOut, part);
    else lossOut[blockIdx.x] = part;
  }
  if (lane < 32)
    out_idx[rowBase + lane] = (float)idx_s[wv][lane];
}

// loss = 2 * sum / (N*D) = sum * 2^-22
__global__ void vq_loss(const float* __restrict__ part, int npart,
                        float* __restrict__ out_loss) {
  float s = 0.f;
  for (int i = threadIdx.x; i < npart; i += 64) s += part[i];
#pragma unroll
  for (int t = 1; t < 64; t <<= 1) s += __shfl_xor(s, t);
  if (threadIdx.x == 0) out_loss[0] = s * (1.0f / 4194304.0f);
}

extern "C" void kernel_launch(void* const* d_in, const int* in_sizes, int n_in,
                              void* d_out, int out_size, void* d_ws, size_t ws_size,
                              hipStream_t stream) {
  const float* x = (const float*)d_in[0];
  const float* w = (const float*)d_in[1];
  float* ob = (float*)d_out;
  float* out_idx = ob;
  float* out_zq = ob + NROWS;
  float* out_ze = out_zq + (size_t)NROWS * DDIM;
  float* out_loss = out_ze + (size_t)NROWS * DDIM;
  float* wsf = (float*)d_ws;

  if (ws_size >= WS_NEED_MFMA) {
    vq_prep_base<<<128, 256, 0, stream>>>(w, wsf + WS_WT, wsf + WS_WSQ);
    vq_prep_bf16<<<128, 256, 0, stream>>>(wsf + WS_WT,
                                          (unsigned short*)(wsf + WS_WTH),
                                          (unsigned short*)(wsf + WS_WTL));
    vq_mfma<<<NBLK, 256, 0, stream>>>(x, wsf + WS_WT, wsf + WS_WSQ,
                                      (const unsigned short*)(wsf + WS_WTH),
                                      (const unsigned short*)(wsf + WS_WTL),
                                      out_idx, out_zq, out_ze, wsf + WS_PART);
    vq_loss<<<1, 64, 0, stream>>>(wsf + WS_PART, NBLK, out_loss);
  } else if (ws_size >= WS_NEED_FALL) {
    vq_prep_base<<<128, 256, 0, stream>>>(w, wsf + WS_WT, wsf + WS_WSQ);
    vq_fb<1, 0><<<NBLK_FB, 256, 0, stream>>>(x, w, wsf + WS_WT, out_idx,
                                             out_zq, out_ze, wsf + WS_PART);
    vq_loss<<<1, 64, 0, stream>>>(wsf + WS_PART, NBLK_FB, out_loss);
  } else {
    hipMemsetAsync(out_loss, 0, sizeof(float), stream);
    vq_fb<0, 1><<<NBLK_FB, 256, 0, stream>>>(x, w, nullptr, out_idx,
                                             out_zq, out_ze, out_loss);
    vq_loss<<<1, 64, 0, stream>>>(out_loss, 1, out_loss);
  }
}